// Round 1
// baseline (696.738 us; speedup 1.0000x reference)
//
#include <hip/hip_runtime.h>
#include <hip/hip_bf16.h>
#include <stdint.h>

#define D_IN 118
#define D_OUT 64
#define KPAD 128
#define BM 128
#define XS_STRIDE 136  // bf16 units; 68 dwords -> quad-phase LDS reads 2-way (free)

typedef __attribute__((ext_vector_type(8))) short bf16x8;
typedef __attribute__((ext_vector_type(4))) float floatx4;

// round-to-nearest-even fp32 -> bf16 (inputs are finite normals)
__device__ __forceinline__ uint16_t f2bf(float f) {
    uint32_t u;
    __builtin_memcpy(&u, &f, 4);
    uint32_t r = (u + 0x7fffu + ((u >> 16) & 1u)) >> 16;
    return (uint16_t)r;
}

__device__ __forceinline__ uint32_t pack_bf16(float a, float b) {
    return (uint32_t)f2bf(a) | ((uint32_t)f2bf(b) << 16);
}

__global__ void wconv(const float* __restrict__ W, ushort* __restrict__ Wt) {
    int idx = blockIdx.x * 256 + threadIdx.x;  // 8192 total
    if (idx >= D_OUT * KPAD) return;
    int o = idx >> 7, k = idx & 127;
    float v = (k < D_IN) ? W[o * D_IN + k] : 0.f;
    Wt[idx] = f2bf(v);
}

__global__ __launch_bounds__(256) void fused_main(
    const float* __restrict__ x, const ushort* __restrict__ Wt,
    const float* __restrict__ bias, const int* __restrict__ batch,
    float* __restrict__ out, int n_atoms)
{
    __shared__ __align__(16) ushort xs[BM * XS_STRIDE];
    __shared__ int ids[BM];

    const int tid = threadIdx.x;
    const int atom0 = blockIdx.x * BM;

    if (tid < BM) {
        int a = atom0 + tid;
        ids[tid] = (a < n_atoms) ? batch[a] : -1;
    }

    // ---- stage x -> bf16 LDS tile [128 atoms x 128 K] ----
    // task tau = (m, c): atom row m, 8-element K-chunk c (8 fp32 -> 8 bf16 = 16 B)
#pragma unroll
    for (int ph = 0; ph < 8; ++ph) {
        int tau = ph * 256 + tid;
        int m = tau >> 4, c = tau & 15;
        long row = atom0 + m;
        bool rok = row < n_atoms;
        const float* src = x + row * D_IN + c * 8;
        uint32_t pk[4];
#pragma unroll
        for (int j = 0; j < 4; ++j) {
            int k = c * 8 + j * 2;  // D_IN even -> a float2 never straddles validity
            float2 v = make_float2(0.f, 0.f);
            if (rok && k < D_IN) v = *reinterpret_cast<const float2*>(src + j * 2);
            pk[j] = pack_bf16(v.x, v.y);
        }
        *reinterpret_cast<uint4*>(&xs[m * XS_STRIDE + c * 8]) =
            make_uint4(pk[0], pk[1], pk[2], pk[3]);
    }

    const int lane = tid & 63;
    const int wv = tid >> 6;
    const int n = lane & 15;   // MFMA A-row / B-col / D-col
    const int q = lane >> 4;   // quad

    // ---- B fragments in registers (Wt is L1/L2-hot, 16 KB) ----
    // B[k][o]: lane holds col o = ot*16+n, k = ks*32 + q*8 + j
    bf16x8 bfrag[4][4];
#pragma unroll
    for (int ot = 0; ot < 4; ++ot)
#pragma unroll
        for (int ks = 0; ks < 4; ++ks) {
            const ushort* p = Wt + (ot * 16 + n) * KPAD + ks * 32 + q * 8;
            bfrag[ot][ks] = *reinterpret_cast<const bf16x8*>(p);
        }

    __syncthreads();

    floatx4 acc[2][4];
#pragma unroll
    for (int mt = 0; mt < 2; ++mt)
#pragma unroll
        for (int ot = 0; ot < 4; ++ot)
            acc[mt][ot] = (floatx4){0.f, 0.f, 0.f, 0.f};

    // ---- MFMA: wave covers atoms [wv*32, wv*32+32) x all 64 outputs ----
#pragma unroll
    for (int ks = 0; ks < 4; ++ks) {
        bf16x8 afrag[2];
#pragma unroll
        for (int mt = 0; mt < 2; ++mt) {
            int row = wv * 32 + mt * 16 + n;  // A[m=lane&15][k=q*8+j]
            afrag[mt] = *reinterpret_cast<const bf16x8*>(
                &xs[row * XS_STRIDE + ks * 32 + q * 8]);
        }
#pragma unroll
        for (int mt = 0; mt < 2; ++mt)
#pragma unroll
            for (int ot = 0; ot < 4; ++ot)
                acc[mt][ot] = __builtin_amdgcn_mfma_f32_16x16x32_bf16(
                    afrag[mt], bfrag[ot][ks], acc[mt][ot], 0, 0, 0);
    }

    // ---- epilogue: bias + relu + sorted-segment flush via atomics ----
    float bv[4];
#pragma unroll
    for (int ot = 0; ot < 4; ++ot) bv[ot] = bias[ot * 16 + n];

    // lane holds D rows r = wv*32 + mt*16 + q*4 + reg, cols ot*16 + n
    float racc[4] = {0.f, 0.f, 0.f, 0.f};
    int cur = ids[wv * 32 + q * 4];
#pragma unroll
    for (int mt = 0; mt < 2; ++mt) {
#pragma unroll
        for (int reg = 0; reg < 4; ++reg) {
            int r = wv * 32 + mt * 16 + q * 4 + reg;
            int id = ids[r];  // same addr across quad -> LDS broadcast
            if (id != cur) {
                if (cur >= 0) {
#pragma unroll
                    for (int ot = 0; ot < 4; ++ot)
                        atomicAdd(&out[cur * 64 + ot * 16 + n], racc[ot]);
                }
                cur = id;
                racc[0] = racc[1] = racc[2] = racc[3] = 0.f;
            }
#pragma unroll
            for (int ot = 0; ot < 4; ++ot) {
                float h = acc[mt][ot][reg] + bv[ot];
                racc[ot] += fmaxf(h, 0.f);
            }
        }
    }
    if (cur >= 0) {
#pragma unroll
        for (int ot = 0; ot < 4; ++ot)
            atomicAdd(&out[cur * 64 + ot * 16 + n], racc[ot]);
    }
}

__global__ void finalize(float* __restrict__ out, int nseg) {
    int row = blockIdx.x * 4 + (threadIdx.x >> 6);
    int lane = threadIdx.x & 63;
    if (row >= nseg) return;
    float v = fmaxf(out[row * 64 + lane], 0.f);
    float m = v;
#pragma unroll
    for (int off = 32; off > 0; off >>= 1)
        m = fmaxf(m, __shfl_xor(m, off, 64));
    out[row * 64 + lane] = v / m;
}

extern "C" void kernel_launch(void* const* d_in, const int* in_sizes, int n_in,
                              void* d_out, int out_size, void* d_ws, size_t ws_size,
                              hipStream_t stream) {
    const float* x = (const float*)d_in[0];
    const float* W = (const float*)d_in[1];
    const float* b = (const float*)d_in[2];
    const int* batch = (const int*)d_in[3];
    // d_in[4] = num_segments scalar (device); host-side value from out_size
    int n_atoms = in_sizes[0] / D_IN;
    int nseg = out_size / D_OUT;
    float* out = (float*)d_out;
    ushort* Wt = (ushort*)d_ws;  // 16 KB

    hipMemsetAsync(d_out, 0, (size_t)out_size * sizeof(float), stream);
    wconv<<<dim3((D_OUT * KPAD + 255) / 256), dim3(256), 0, stream>>>(W, Wt);
    int nblocks = (n_atoms + BM - 1) / BM;
    fused_main<<<dim3(nblocks), dim3(256), 0, stream>>>(x, Wt, b, batch, out, n_atoms);
    finalize<<<dim3((nseg + 3) / 4), dim3(256), 0, stream>>>(out, nseg);
}

// Round 2
// 652.531 us; speedup vs baseline: 1.0677x; 1.0677x over previous
//
#include <hip/hip_runtime.h>
#include <hip/hip_bf16.h>
#include <stdint.h>

#define D_IN 118
#define D_OUT 64
#define KPAD 128
#define BM 128
#define XS_STRIDE 136  // bf16 units; 68 dwords -> quad-phase LDS reads 2-way (free)
#define MAXSEG 16      // max segment span handled via LDS pre-reduction

typedef __attribute__((ext_vector_type(8))) short bf16x8;
typedef __attribute__((ext_vector_type(4))) float floatx4;

// round-to-nearest-even fp32 -> bf16 (inputs are finite normals)
__device__ __forceinline__ uint16_t f2bf(float f) {
    uint32_t u;
    __builtin_memcpy(&u, &f, 4);
    uint32_t r = (u + 0x7fffu + ((u >> 16) & 1u)) >> 16;
    return (uint16_t)r;
}

__device__ __forceinline__ uint32_t pack_bf16(float a, float b) {
    return (uint32_t)f2bf(a) | ((uint32_t)f2bf(b) << 16);
}

__global__ void wconv(const float* __restrict__ W, ushort* __restrict__ Wt) {
    int idx = blockIdx.x * 256 + threadIdx.x;  // 8192 total
    if (idx >= D_OUT * KPAD) return;
    int o = idx >> 7, k = idx & 127;
    float v = (k < D_IN) ? W[o * D_IN + k] : 0.f;
    Wt[idx] = f2bf(v);
}

__global__ __launch_bounds__(256) void fused_main(
    const float* __restrict__ x, const ushort* __restrict__ Wt,
    const float* __restrict__ bias, const int* __restrict__ batch,
    float* __restrict__ out, int n_atoms)
{
    __shared__ __align__(16) ushort xs[BM * XS_STRIDE];  // 34 KB
    __shared__ int ids[BM];
    __shared__ float segacc[MAXSEG * 64];                // 4 KB

    const int tid = threadIdx.x;
    const int atom0 = blockIdx.x * BM;

    if (tid < BM) {
        int a = atom0 + tid;
        ids[tid] = (a < n_atoms) ? batch[a] : -1;
    }

    // zero the per-block segment accumulator (before the barrier)
#pragma unroll
    for (int i = 0; i < (MAXSEG * 64) / 256; ++i)
        segacc[i * 256 + tid] = 0.0f;

    // ---- stage x -> bf16 LDS tile [128 atoms x 128 K] ----
#pragma unroll
    for (int ph = 0; ph < 8; ++ph) {
        int tau = ph * 256 + tid;
        int m = tau >> 4, c = tau & 15;
        long row = atom0 + m;
        bool rok = row < n_atoms;
        const float* src = x + row * D_IN + c * 8;
        uint32_t pk[4];
#pragma unroll
        for (int j = 0; j < 4; ++j) {
            int k = c * 8 + j * 2;  // D_IN even -> a float2 never straddles validity
            float2 v = make_float2(0.f, 0.f);
            if (rok && k < D_IN) v = *reinterpret_cast<const float2*>(src + j * 2);
            pk[j] = pack_bf16(v.x, v.y);
        }
        *reinterpret_cast<uint4*>(&xs[m * XS_STRIDE + c * 8]) =
            make_uint4(pk[0], pk[1], pk[2], pk[3]);
    }

    const int lane = tid & 63;
    const int wv = tid >> 6;
    const int n = lane & 15;   // MFMA A-row / B-col / D-col
    const int q = lane >> 4;   // quad

    // ---- B fragments in registers (Wt is L1/L2-hot, 16 KB) ----
    bf16x8 bfrag[4][4];
#pragma unroll
    for (int ot = 0; ot < 4; ++ot)
#pragma unroll
        for (int ks = 0; ks < 4; ++ks) {
            const ushort* p = Wt + (ot * 16 + n) * KPAD + ks * 32 + q * 8;
            bfrag[ot][ks] = *reinterpret_cast<const bf16x8*>(p);
        }

    __syncthreads();

    // segment span of this block (ids sorted; -1 only in tail padding)
    int s_first = ids[0];
    int vmax = max(ids[lane], ids[64 + lane]);
#pragma unroll
    for (int off = 32; off > 0; off >>= 1)
        vmax = max(vmax, __shfl_xor(vmax, off, 64));
    const int span = vmax - s_first + 1;
    const bool use_lds = (span <= MAXSEG);

    floatx4 acc[2][4];
#pragma unroll
    for (int mt = 0; mt < 2; ++mt)
#pragma unroll
        for (int ot = 0; ot < 4; ++ot)
            acc[mt][ot] = (floatx4){0.f, 0.f, 0.f, 0.f};

    // ---- MFMA: wave covers atoms [wv*32, wv*32+32) x all 64 outputs ----
#pragma unroll
    for (int ks = 0; ks < 4; ++ks) {
        bf16x8 afrag[2];
#pragma unroll
        for (int mt = 0; mt < 2; ++mt) {
            int row = wv * 32 + mt * 16 + n;  // A[m=lane&15][k=q*8+j]
            afrag[mt] = *reinterpret_cast<const bf16x8*>(
                &xs[row * XS_STRIDE + ks * 32 + q * 8]);
        }
#pragma unroll
        for (int mt = 0; mt < 2; ++mt)
#pragma unroll
            for (int ot = 0; ot < 4; ++ot)
                acc[mt][ot] = __builtin_amdgcn_mfma_f32_16x16x32_bf16(
                    afrag[mt], bfrag[ot][ks], acc[mt][ot], 0, 0, 0);
    }

    // ---- epilogue: bias + relu + per-lane runs -> LDS segacc -> global ----
    float bv[4];
#pragma unroll
    for (int ot = 0; ot < 4; ++ot) bv[ot] = bias[ot * 16 + n];

    float racc[4] = {0.f, 0.f, 0.f, 0.f};
    int cur = ids[wv * 32 + q * 4];
#pragma unroll
    for (int mt = 0; mt < 2; ++mt) {
#pragma unroll
        for (int reg = 0; reg < 4; ++reg) {
            int r = wv * 32 + mt * 16 + q * 4 + reg;
            int id = ids[r];  // same addr across quad -> LDS broadcast
            if (id != cur) {
                if (cur >= 0) {
                    if (use_lds) {
                        int base = (cur - s_first) * 64 + n;
#pragma unroll
                        for (int ot = 0; ot < 4; ++ot)
                            atomicAdd(&segacc[base + ot * 16], racc[ot]);
                    } else {
#pragma unroll
                        for (int ot = 0; ot < 4; ++ot)
                            atomicAdd(&out[cur * 64 + ot * 16 + n], racc[ot]);
                    }
                }
                cur = id;
                racc[0] = racc[1] = racc[2] = racc[3] = 0.f;
            }
#pragma unroll
            for (int ot = 0; ot < 4; ++ot) {
                float h = acc[mt][ot][reg] + bv[ot];
                racc[ot] += fmaxf(h, 0.f);
            }
        }
    }
    if (cur >= 0) {
        if (use_lds) {
            int base = (cur - s_first) * 64 + n;
#pragma unroll
            for (int ot = 0; ot < 4; ++ot)
                atomicAdd(&segacc[base + ot * 16], racc[ot]);
        } else {
#pragma unroll
            for (int ot = 0; ot < 4; ++ot)
                atomicAdd(&out[cur * 64 + ot * 16 + n], racc[ot]);
        }
    }

    // ---- flush block-level segment sums to global (1 atomic per seg-col) ----
    __syncthreads();
    if (use_lds) {
        for (int i = tid; i < span * 64; i += 256) {
            float v = segacc[i];
            if (v != 0.0f)
                atomicAdd(&out[(s_first + (i >> 6)) * 64 + (i & 63)], v);
        }
    }
}

__global__ void finalize(float* __restrict__ out, int nseg) {
    int row = blockIdx.x * 4 + (threadIdx.x >> 6);
    int lane = threadIdx.x & 63;
    if (row >= nseg) return;
    float v = fmaxf(out[row * 64 + lane], 0.f);
    float m = v;
#pragma unroll
    for (int off = 32; off > 0; off >>= 1)
        m = fmaxf(m, __shfl_xor(m, off, 64));
    out[row * 64 + lane] = v / m;
}

extern "C" void kernel_launch(void* const* d_in, const int* in_sizes, int n_in,
                              void* d_out, int out_size, void* d_ws, size_t ws_size,
                              hipStream_t stream) {
    const float* x = (const float*)d_in[0];
    const float* W = (const float*)d_in[1];
    const float* b = (const float*)d_in[2];
    const int* batch = (const int*)d_in[3];
    int n_atoms = in_sizes[0] / D_IN;
    int nseg = out_size / D_OUT;
    float* out = (float*)d_out;
    ushort* Wt = (ushort*)d_ws;  // 16 KB

    hipMemsetAsync(d_out, 0, (size_t)out_size * sizeof(float), stream);
    wconv<<<dim3((D_OUT * KPAD + 255) / 256), dim3(256), 0, stream>>>(W, Wt);
    int nblocks = (n_atoms + BM - 1) / BM;
    fused_main<<<dim3(nblocks), dim3(256), 0, stream>>>(x, Wt, b, batch, out, n_atoms);
    finalize<<<dim3((nseg + 3) / 4), dim3(256), 0, stream>>>(out, nseg);
}